// Round 3
// baseline (2076.453 us; speedup 1.0000x reference)
//
#include <hip/hip_runtime.h>

// HMM scaled-forward, A fully register-resident.
// 128 wgs (one per (m,b)) x 1024 threads = 8 q-groups x 128 col-threads.
// A[m] (512x512, f16 q-pairs) packed once; each thread owns 4 cols x 32
// q-pairs = 32 x h8 chunks, ALL in VGPR/AGPR (~128 regs). Per step:
//   phase1: 128 x dot2 per thread, partials -> red[qg][k] (b128, conflict-free)
//   barrier; phase2 (512 thr): S from red2[prev] + 8-way reduce + renorm +
//   pack new u (f16) + wave-sum -> red2[cur]; barrier.
// No per-step global A traffic, no LDS A traffic, no serial epilogue.

typedef _Float16 h2 __attribute__((ext_vector_type(2)));
typedef _Float16 h8 __attribute__((ext_vector_type(8)));

constexpr int Q = 512;
constexpr int L = 512;
constexpr int M = 2;
constexpr int B = 64;
constexpr int NTH = 1024;     // 8 q-groups x 128 col-threads
constexpr int CHUNKS = 32;    // h8 chunks per thread (all in regs)
constexpr float EPS = 1e-16f;

__device__ __forceinline__ float fdot2(h2 a, h2 b, float c) {
#if __has_builtin(__builtin_amdgcn_fdot2)
    return __builtin_amdgcn_fdot2(a, b, c, false);
#else
    return fmaf((float)a.x, (float)b.x, fmaf((float)a.y, (float)b.y, c));
#endif
}

// pack A (M,Q,Q) f32 -> per-thread chunk layout, f16 pairs over q.
// chunk c of thread t (qg=t>>7, ct=t&127): word j = (A[m][qg*64+2c][4ct+j],
// A[m][qg*64+2c+1][4ct+j]), stored at wsA[(m*32+c)*1024 + t].
__global__ __launch_bounds__(256) void pack_A(const float* __restrict__ A,
                                              uint4* __restrict__ wsA) {
    int idx = blockIdx.x * 256 + threadIdx.x;
    int t = idx & (NTH - 1);
    int c = (idx >> 10) & (CHUNKS - 1);
    int m = idx >> 15;
    int qg = t >> 7, ct = t & 127;
    int q0 = qg * 64 + 2 * c;
    const float* a0 = A + ((size_t)m * Q + q0) * Q + 4 * ct;
    float4 r0 = *(const float4*)a0;
    float4 r1 = *(const float4*)(a0 + Q);
    union { h2 w[4]; uint4 v; } cv;
    cv.w[0].x = (_Float16)r0.x; cv.w[0].y = (_Float16)r1.x;
    cv.w[1].x = (_Float16)r0.y; cv.w[1].y = (_Float16)r1.y;
    cv.w[2].x = (_Float16)r0.z; cv.w[2].y = (_Float16)r1.z;
    cv.w[3].x = (_Float16)r0.w; cv.w[3].y = (_Float16)r1.w;
    wsA[idx] = cv.v;
}

__global__ __launch_bounds__(NTH) void hmm_fwd(
    const float* __restrict__ emis,   // (L, M, B, Q)
    const uint4* __restrict__ wsA,    // packed A
    const float* __restrict__ initd,  // (M, Q)
    float* __restrict__ out)          // (M, B)
{
    __shared__ h2    ldsU[Q / 2];     // u (f16 pairs), 1 KB
    __shared__ float red[8 * Q];      // per-qg partials, 16 KB
    __shared__ float red2[2][8];      // per-wave sums, parity double-buffered

    const int t   = threadIdx.x;
    const int bid = blockIdx.x;       // m*B + b
    const int m   = bid >> 6;
    const int qg  = t >> 7;

    // ---- one-time A staging: all 32 chunks -> registers ----
    const uint4* wa = wsA + (size_t)m * CHUNKS * NTH + t;
    h8 areg[CHUNKS];
    #pragma unroll
    for (int c = 0; c < CHUNKS; ++c)
        areg[c] = *(const h8*)(wa + (size_t)c * NTH);

    const float* E = emis + (size_t)bid * Q;       // (t=0, m, b, :)
    const size_t stepStride = (size_t)M * B * Q;

    float ll = 0.0f;

    // ---- init: u0 = max(E0,eps) * max(init,eps), one state per thread ----
    if (t < Q) {
        float u = fmaxf(E[t], EPS) * fmaxf(initd[m * Q + t], EPS);
        float uy = __shfl_xor(u, 1, 64);
        if (!(t & 1)) { h2 w; w.x = (_Float16)u; w.y = (_Float16)uy; ldsU[t >> 1] = w; }
        float s = u;
        #pragma unroll
        for (int off = 32; off >= 1; off >>= 1) s += __shfl_xor(s, off, 64);
        if ((t & 63) == 0) red2[0][t >> 6] = s;
    }
    __syncthreads();

    const float* Ep = E + stepStride + t;   // E[step][...][t], step=1

    for (int step = 1; step < L; ++step) {
        const int pp = (step + 1) & 1;      // red2 buffer holding S(step-1)
        const int cp = step & 1;

        float ep = 0.0f;
        if (t < Q) ep = *Ep;
        Ep += stepStride;

        // ---- phase1: 4 output cols x 64 q of my q-group, all from regs ----
        float a0 = 0.f, a1 = 0.f, a2 = 0.f, a3 = 0.f;
        const h8* uq8 = (const h8*)(ldsU + qg * 32);   // wave-uniform broadcast
        #pragma unroll
        for (int i = 0; i < 8; ++i) {
            h8 uw = uq8[i];
            h2 up0 = uw.lo.lo, up1 = uw.lo.hi, up2 = uw.hi.lo, up3 = uw.hi.hi;
            a0 = fdot2(areg[4 * i + 0].lo.lo, up0, a0);
            a1 = fdot2(areg[4 * i + 0].lo.hi, up0, a1);
            a2 = fdot2(areg[4 * i + 0].hi.lo, up0, a2);
            a3 = fdot2(areg[4 * i + 0].hi.hi, up0, a3);
            a0 = fdot2(areg[4 * i + 1].lo.lo, up1, a0);
            a1 = fdot2(areg[4 * i + 1].lo.hi, up1, a1);
            a2 = fdot2(areg[4 * i + 1].hi.lo, up1, a2);
            a3 = fdot2(areg[4 * i + 1].hi.hi, up1, a3);
            a0 = fdot2(areg[4 * i + 2].lo.lo, up2, a0);
            a1 = fdot2(areg[4 * i + 2].lo.hi, up2, a1);
            a2 = fdot2(areg[4 * i + 2].hi.lo, up2, a2);
            a3 = fdot2(areg[4 * i + 2].hi.hi, up2, a3);
            a0 = fdot2(areg[4 * i + 3].lo.lo, up3, a0);
            a1 = fdot2(areg[4 * i + 3].lo.hi, up3, a1);
            a2 = fdot2(areg[4 * i + 3].hi.lo, up3, a2);
            a3 = fdot2(areg[4 * i + 3].hi.hi, up3, a3);
        }
        float4 rv; rv.x = a0; rv.y = a1; rv.z = a2; rv.w = a3;
        *(float4*)(&red[qg * Q + 4 * (t & 127)]) = rv;
        __syncthreads();

        // ---- phase2 (t<512): S(prev), reduce 8 qg, renorm, new u, wave-sum ----
        if (t < Q) {
            float4 rA = *(const float4*)&red2[pp][0];
            float4 rB = *(const float4*)&red2[pp][4];
            float acc = 0.f;
            #pragma unroll
            for (int g = 0; g < 8; ++g) acc += red[g * Q + t];
            float Sv = ((rA.x + rA.y) + (rA.z + rA.w)) +
                       ((rB.x + rB.y) + (rB.z + rB.w));
            float inv = 1.0f / Sv;
            ll += __logf(Sv);
            float r = fmaxf(acc * inv, EPS);
            float e = fmaxf(ep, EPS);
            float u = e * r;
            float uy = __shfl_xor(u, 1, 64);
            if (!(t & 1)) { h2 w; w.x = (_Float16)u; w.y = (_Float16)uy; ldsU[t >> 1] = w; }
            float s = u;
            #pragma unroll
            for (int off = 32; off >= 1; off >>= 1) s += __shfl_xor(s, off, 64);
            if ((t & 63) == 0) red2[cp][t >> 6] = s;
        }
        __syncthreads();
    }

    if (t == 0) {
        const float* r2 = red2[(L - 1) & 1];
        float Sv = ((r2[0] + r2[1]) + (r2[2] + r2[3])) +
                   ((r2[4] + r2[5]) + (r2[6] + r2[7]));
        out[bid] = ll + __logf(Sv);
    }
}

// ---- fallback (round-1 kernel) if ws is too small for packed A ----
__global__ __launch_bounds__(512) void hmm_forward_fb(
    const float* __restrict__ emis, const float* __restrict__ Aall,
    const float* __restrict__ initd, float* __restrict__ out)
{
    const int bid = blockIdx.x;
    const int m = bid / B;
    const int k = threadIdx.x;
    const int lane = k & 63, wid = k >> 6;
    const float* Am = Aall + (size_t)m * Q * Q;
    const float* E = emis + (size_t)bid * Q;
    const size_t stepStride = (size_t)M * B * Q;
    __shared__ float u_lds[Q];
    __shared__ float redf[8];
    float e = fmaxf(E[k], EPS);
    float r = fmaxf(initd[m * Q + k], EPS);
    float uval = e * r;
    float ll = 0.0f, invS = 1.0f;
    for (int t = 1; t <= L; ++t) {
        float ws = uval;
        #pragma unroll
        for (int off = 32; off >= 1; off >>= 1) ws += __shfl_xor(ws, off, 64);
        __syncthreads();
        u_lds[k] = uval;
        if (lane == 0) redf[wid] = ws;
        __syncthreads();
        float S = 0.0f;
        #pragma unroll
        for (int w = 0; w < 8; ++w) S += redf[w];
        ll += __logf(S);
        invS = 1.0f / S;
        if (t == L) break;
        float acc = 0.0f;
        #pragma unroll 8
        for (int q = 0; q < Q; ++q)
            acc = fmaf(u_lds[q], Am[q * Q + k], acc);
        float rr = fmaxf(acc * invS, EPS);
        float ee = fmaxf(E[(size_t)t * stepStride + k], EPS);
        uval = ee * rr;
    }
    if (k == 0) out[bid] = ll;
}

extern "C" void kernel_launch(void* const* d_in, const int* in_sizes, int n_in,
                              void* d_out, int out_size, void* d_ws, size_t ws_size,
                              hipStream_t stream) {
    const float* emis  = (const float*)d_in[0];  // (L, M, B, Q)
    const float* A     = (const float*)d_in[1];  // (M, Q, Q)
    const float* initd = (const float*)d_in[2];  // (M, Q)
    float* out = (float*)d_out;                  // (M, B)

    const size_t wsNeeded = (size_t)M * CHUNKS * NTH * 16;  // 1 MB
    if (ws_size < wsNeeded) {
        hipLaunchKernelGGL(hmm_forward_fb, dim3(M * B), dim3(512), 0, stream,
                           emis, A, initd, out);
        return;
    }

    uint4* wsA = (uint4*)d_ws;
    hipLaunchKernelGGL(pack_A, dim3(M * CHUNKS * NTH / 256), dim3(256), 0,
                       stream, A, wsA);
    hipLaunchKernelGGL(hmm_fwd, dim3(M * B), dim3(NTH), 0, stream,
                       emis, wsA, initd, out);
}